// Round 1
// baseline (353.695 us; speedup 1.0000x reference)
//
#include <hip/hip_runtime.h>

typedef short bf16x8 __attribute__((ext_vector_type(8)));
typedef float f32x4  __attribute__((ext_vector_type(4)));

static __device__ __forceinline__ unsigned short f2bf(float f) {
    unsigned int u = __builtin_bit_cast(unsigned int, f);
    u += 0x7FFFu + ((u >> 16) & 1u);   // round-to-nearest-even
    return (unsigned short)(u >> 16);
}

// ---------------- Kernel 1: demodulate + convert weights to bf16 -------------
// out layout: wn[((tap*4 + ci_chunk)*128 + co)*32 + ci_in_chunk]  (bf16 bits)
__global__ __launch_bounds__(256) void prep_w_k(const float* __restrict__ w,
                                                unsigned short* __restrict__ wn) {
    const int co = blockIdx.x;
    const int t  = threadIdx.x;
    const float* wc = w + co * 3456;
    float s = 0.f;
    for (int i = t; i < 3456; i += 256) { float v = wc[i]; s += v * v; }
#pragma unroll
    for (int off = 32; off; off >>= 1) s += __shfl_down(s, off);
    __shared__ float red[4];
    __shared__ float dsh;
    if ((t & 63) == 0) red[t >> 6] = s;
    __syncthreads();
    if (t == 0) dsh = rsqrtf(red[0] + red[1] + red[2] + red[3] + 1e-8f);
    __syncthreads();
    const float d = dsh;
    for (int i = t; i < 3456; i += 256) {
        int ci = i / 27, tap = i - ci * 27;
        float v = wc[i] * d;
        wn[((tap * 4 + (ci >> 5)) * 128 + co) * 32 + (ci & 31)] = f2bf(v);
    }
}

// ---------------- Kernel 2: implicit-GEMM conv3d + epilogue ------------------
// Block: 512 thr = 8 waves (4 M-rows x 2 N-cols). Tile M=512 (d4,h4,w32), N=128.
// LDS: bs (2 x 128co x (32ci+8pad) bf16)  slots 0..1279
//      xs (1224 pos x (32ci+8pad) bf16)   slots 1280..7399
#define XSBASE 1280
__global__ __launch_bounds__(512, 2) void conv3d_k(
    const float* __restrict__ x, const unsigned short* __restrict__ wn,
    const float* __restrict__ bias, float* __restrict__ out) {
    __shared__ __align__(16) unsigned short lds[59200];

    const int t    = threadIdx.x;
    const int lane = t & 63;
    const int wid  = t >> 6;
    const int wr   = wid >> 1;     // 0..3 : d-slice of tile
    const int wcn  = wid & 1;      // 0..1 : co half
    const int ll   = lane & 15;
    const int g    = lane >> 4;    // 0..3 : k-group / co-quad group

    const int bid = blockIdx.x;
    const int b  = bid >> 6;
    const int dt = (bid >> 3) & 7, ht = bid & 7;
    const int d0 = dt * 4, h0 = ht * 4;

    // staging constants
    const int sw  = t & 31;          // w
    const int sg  = (t >> 5) & 3;    // ci group (8 ci)
    const int rhi = t >> 7;          // 0..3
    const int bco = t >> 2, bgb = t & 3;

    f32x4 acc[8][4];
#pragma unroll
    for (int i = 0; i < 8; ++i)
#pragma unroll
        for (int j = 0; j < 4; ++j) acc[i][j] = (f32x4){0.f, 0.f, 0.f, 0.f};

    // bias registers (co = wcn*64 + nf*16 + g*4 + q)
    float bv[4][4];
#pragma unroll
    for (int nf = 0; nf < 4; ++nf) {
        f32x4 bb = *(const f32x4*)&bias[wcn * 64 + nf * 16 + g * 4];
#pragma unroll
        for (int q = 0; q < 4; ++q) bv[nf][q] = bb[q];
    }

    // zero the w-edge columns of xs once (wx==0 and wx==33 never re-written)
    if (t < 288) {
        int pi  = t >> 2;                 // 0..71
        int row = pi >> 1;                // 0..35
        int pos = row * 34 + (pi & 1) * 33;
        bf16x8 z = {0, 0, 0, 0, 0, 0, 0, 0};
        *(bf16x8*)&lds[(XSBASE + pos * 5 + (t & 3)) * 8] = z;
    }

    for (int c = 0; c < 4; ++c) {
        const int cibase = c * 32;
        // ---- stage x halo chunk (transpose w-major global -> ci-major LDS) ----
#pragma unroll
        for (int p = 0; p < 9; ++p) {
            int rowid = p * 4 + rhi;               // 0..35
            int pd = (rowid * 43) >> 8;            // /6
            int ph = rowid - pd * 6;
            int d = d0 - 1 + pd, h = h0 - 1 + ph;
            bool ok = ((unsigned)d < 32u) && ((unsigned)h < 32u);
            const float* src = x + (((b * 128 + cibase + sg * 8) * 32 + d) * 32 + h) * 32 + sw;
            float v[8];
#pragma unroll
            for (int j = 0; j < 8; ++j) v[j] = ok ? src[j * 32768] : 0.f;
            bf16x8 pk;
#pragma unroll
            for (int j = 0; j < 8; ++j) pk[j] = (short)f2bf(v[j]);
            int pos = (pd * 6 + ph) * 34 + sw + 1;
            *(bf16x8*)&lds[(XSBASE + pos * 5 + sg) * 8] = pk;
        }
        // ---- stage B (tap 0) into buf 0 ----
        {
            bf16x8 bw = *(const bf16x8*)&wn[(0 * 4 + c) * 4096 + t * 8];
            *(bf16x8*)&lds[(bco * 5 + bgb) * 8] = bw;
        }
        __syncthreads();

#pragma unroll
        for (int tap = 0; tap < 27; ++tap) {
            const int od = tap / 9, oh = (tap / 3) % 3, ow = tap % 3;
            bf16x8 pref;
            if (tap < 26) pref = *(const bf16x8*)&wn[((tap + 1) * 4 + c) * 4096 + t * 8];

            const int bufo = (tap & 1) * 640;
            bf16x8 wf[4];
#pragma unroll
            for (int nf = 0; nf < 4; ++nf)
                wf[nf] = *(const bf16x8*)&lds[(bufo + (wcn * 64 + nf * 16 + ll) * 5 + g) * 8];

#pragma unroll
            for (int mf = 0; mf < 8; ++mf) {
                const int pd = wr + od;
                const int ph = (mf >> 1) + oh;
                const int wx = (mf & 1) * 16 + ll + ow;     // (w + ow - 1) + 1
                const int pos = (pd * 6 + ph) * 34 + wx;
                const bf16x8 xf = *(const bf16x8*)&lds[(XSBASE + pos * 5 + g) * 8];
#pragma unroll
                for (int nf = 0; nf < 4; ++nf)
                    acc[mf][nf] = __builtin_amdgcn_mfma_f32_16x16x32_bf16(
                        wf[nf], xf, acc[mf][nf], 0, 0, 0);
            }

            if (tap < 26)
                *(bf16x8*)&lds[(((tap + 1) & 1) * 640 + bco * 5 + bgb) * 8] = pref;
            __syncthreads();
        }
    }

    // ---- epilogue: bias + leaky_relu + gain + clamp, coalesced along w ----
    const int dd = d0 + wr;
#pragma unroll
    for (int mf = 0; mf < 8; ++mf) {
        const int hh = h0 + (mf >> 1);
        const int ww = (mf & 1) * 16 + ll;
#pragma unroll
        for (int nf = 0; nf < 4; ++nf) {
#pragma unroll
            for (int q = 0; q < 4; ++q) {
                const int co = wcn * 64 + nf * 16 + g * 4 + q;
                float v = acc[mf][nf][q] + bv[nf][q];
                v = v > 0.f ? v : v * 0.2f;
                v *= 1.41421356237f;
                v = fminf(fmaxf(v, -256.f), 256.f);
                out[(b * 128 + co) * 32768 + dd * 1024 + hh * 32 + ww] = v;
            }
        }
    }
}

extern "C" void kernel_launch(void* const* d_in, const int* in_sizes, int n_in,
                              void* d_out, int out_size, void* d_ws, size_t ws_size,
                              hipStream_t stream) {
    const float* x    = (const float*)d_in[0];
    const float* w    = (const float*)d_in[1];
    const float* bias = (const float*)d_in[2];
    float* out        = (float*)d_out;
    unsigned short* wn = (unsigned short*)d_ws;   // 27*128*128 bf16 = 884736 B

    prep_w_k<<<128, 256, 0, stream>>>(w, wn);
    conv3d_k<<<512, 512, 0, stream>>>(x, wn, bias, out);
}